// Round 3
// baseline (80.605 us; speedup 1.0000x reference)
//
#include <hip/hip_runtime.h>

// 5-qubit state: index = a*16 + b*8 + c*4 + d*2 + e
// wire0=a=bit4, wire1=b=bit3, wire2=c=bit2, wire3=d=bit1, wire4=e=bit0
//
// Key structure: RX gates act on wires 1-4 (bits 3..0) and CU gates act on
// bit pairs (3,2),(2,1),(1,0),(0,3) -- NONE touch bit4. Only CPhase (wires
// 0,1 = bits 4,3) and the final H touch bit4. Hence the two bit4-halves see
// identical linear evolution and differ only by accumulated CPhase factors.
// Track u = a=0 half, w = a=1 half as 16-amplitude states over bits 3..0.
// <Z0> after final H = sum_m Re(u_m conj(w_m))  (normalization cancels).

__device__ __forceinline__ void sc_half(float ang, float& s, float& c) {
    const float r = ang * 0.07957747154594767f;   // (ang/2) / (2*pi)
    s = __builtin_amdgcn_sinf(r);
    c = __builtin_amdgcn_cosf(r);
}
__device__ __forceinline__ void sc_full(float ang, float& s, float& c) {
    const float r = ang * 0.15915494309189535f;   // ang / (2*pi)
    s = __builtin_amdgcn_sinf(r);
    c = __builtin_amdgcn_cosf(r);
}

// RX on BIT of a 16-amp (4-bit) state: gate [[c,-is],[-is,c]]
template<int BIT>
__device__ __forceinline__ void rx16(float (&sr)[16], float (&si)[16],
                                     float c, float s) {
#pragma unroll
    for (int m = 0; m < 8; ++m) {
        const int lo = m & ((1 << BIT) - 1);
        const int hi = (m >> BIT) << (BIT + 1);
        const int i0 = hi | lo;
        const int i1 = i0 | (1 << BIT);
        const float ar = sr[i0], ai = si[i0];
        const float br = sr[i1], bi = si[i1];
        sr[i0] = c * ar + s * bi;
        si[i0] = c * ai - s * br;
        sr[i1] = s * ai + c * br;
        si[i1] = c * bi - s * ar;
    }
}

// controlled-X_theta on (CBIT -> TBIT) of a 16-amp state.
// For ctrl==1: (t0,t1) -> (u01*t1, u10*t0), u01 = sn - i*cs, u10 = -sn - i*cs.
template<int CBIT, int TBIT>
__device__ __forceinline__ void cu16(float (&sr)[16], float (&si)[16],
                                     float sn, float cs) {
#pragma unroll
    for (int m = 0; m < 8; ++m) {
        const int lo = m & ((1 << TBIT) - 1);
        const int hi = (m >> TBIT) << (TBIT + 1);
        const int i0 = hi | lo;
        if (!(i0 & (1 << CBIT))) continue;   // compile-time eliminated
        const int i1 = i0 | (1 << TBIT);
        const float ar = sr[i0], ai = si[i0];
        const float br = sr[i1], bi = si[i1];
        // i0' = u01 * b = (sn - i cs)(br + i bi)
        sr[i0] = sn * br + cs * bi;
        si[i0] = sn * bi - cs * br;
        // i1' = u10 * a = (-sn - i cs)(ar + i ai)
        sr[i1] = cs * ai - sn * ar;
        si[i1] = -(sn * ai + cs * ar);
    }
}

__global__ __launch_bounds__(256)
void qsim_kernel(const float* __restrict__ x,
                 const float* __restrict__ thetas,
                 const float* __restrict__ phis,
                 float* __restrict__ out, int P) {
    const int p = blockIdx.x * blockDim.x + threadIdx.x;
    if (p >= P) return;

    const int b   = p >> 14;
    const int rem = p & 16383;
    const int i   = rem >> 7;
    const int j   = rem & 127;

    // 12 patch pixels: pix[4*c + 2*dy + dx] = x[b, c, 2i+dy, 2j+dx]
    float pix[12];
    const float2* __restrict__ x2 = (const float2*)x;
#pragma unroll
    for (int c = 0; c < 3; ++c) {
#pragma unroll
        for (int dy = 0; dy < 2; ++dy) {
            const int row = (b * 3 + c) * 256 + (2 * i + dy);
            const float2 v = x2[row * 128 + j];
            pix[c * 4 + dy * 2 + 0] = v.x;
            pix[c * 4 + dy * 2 + 1] = v.y;
        }
    }

    // ---- layer 1 on the shared half h (H + RX folded into init) ----
    // h(m) = prod over bits of (cos | -i*sin)(pix/2) = mag * (-i)^popcount(m)
    float ur[16], ui[16];
    {
        float s1, c1, s2, c2, s3, c3, s4, c4;
        sc_half(pix[0], s1, c1);
        sc_half(pix[1], s2, c2);
        sc_half(pix[2], s3, c3);
        sc_half(pix[3], s4, c4);
        const float pA[4] = {c1 * c2, c1 * s2, s1 * c2, s1 * s2}; // bits 3,2
        const float pB[4] = {c3 * c4, c3 * s4, s3 * c4, s3 * s4}; // bits 1,0
#pragma unroll
        for (int m = 0; m < 16; ++m) {
            const float v = pA[m >> 2] * pB[m & 3];
            const int pc = __builtin_popcount((unsigned)m) & 3;
            ur[m] = (pc == 0) ? v : ((pc == 2) ? -v : 0.f);
            ui[m] = (pc == 1) ? -v : ((pc == 3) ? v : 0.f);
        }
    }
    // layer-1 CU gates on h (stored in u)
    {
        float sn, cs;
        sc_half(thetas[0], sn, cs); cu16<3, 2>(ur, ui, sn, cs);
        sc_half(thetas[1], sn, cs); cu16<2, 1>(ur, ui, sn, cs);
        sc_half(thetas[2], sn, cs); cu16<1, 0>(ur, ui, sn, cs);
        sc_half(thetas[3], sn, cs); cu16<0, 3>(ur, ui, sn, cs);
    }
    // split: u = h ; w = h with CPhase(phi0) on bit3=1 amps
    float wr[16], wi[16];
    {
        float sn, cs;
        sc_full(phis[0], sn, cs);
#pragma unroll
        for (int m = 0; m < 16; ++m) {
            if (m & 8) {
                wr[m] = cs * ur[m] - sn * ui[m];
                wi[m] = cs * ui[m] + sn * ur[m];
            } else {
                wr[m] = ur[m];
                wi[m] = ui[m];
            }
        }
    }

    // ---- layers 2,3: identical gates on u and w; CPhase on w only ----
#pragma unroll
    for (int L = 1; L < 3; ++L) {
        float sn, cs;
        sc_half(pix[4 * L + 0], sn, cs);
        rx16<3>(ur, ui, cs, sn); rx16<3>(wr, wi, cs, sn);
        sc_half(pix[4 * L + 1], sn, cs);
        rx16<2>(ur, ui, cs, sn); rx16<2>(wr, wi, cs, sn);
        sc_half(pix[4 * L + 2], sn, cs);
        rx16<1>(ur, ui, cs, sn); rx16<1>(wr, wi, cs, sn);
        sc_half(pix[4 * L + 3], sn, cs);
        rx16<0>(ur, ui, cs, sn); rx16<0>(wr, wi, cs, sn);

        sc_half(thetas[4 * L + 0], sn, cs);
        cu16<3, 2>(ur, ui, sn, cs); cu16<3, 2>(wr, wi, sn, cs);
        sc_half(thetas[4 * L + 1], sn, cs);
        cu16<2, 1>(ur, ui, sn, cs); cu16<2, 1>(wr, wi, sn, cs);
        sc_half(thetas[4 * L + 2], sn, cs);
        cu16<1, 0>(ur, ui, sn, cs); cu16<1, 0>(wr, wi, sn, cs);
        sc_half(thetas[4 * L + 3], sn, cs);
        cu16<0, 3>(ur, ui, sn, cs); cu16<0, 3>(wr, wi, sn, cs);

        sc_full(phis[L], sn, cs);
#pragma unroll
        for (int m = 8; m < 16; ++m) {   // bit3=1 amps of w
            const float ar = wr[m], ai = wi[m];
            wr[m] = cs * ar - sn * ai;
            wi[m] = cs * ai + sn * ar;
        }
    }

    // <Z0> = sum_m Re(u_m * conj(w_m))
    float ev = 0.f;
#pragma unroll
    for (int m = 0; m < 16; ++m) {
        ev += ur[m] * wr[m] + ui[m] * wi[m];
    }
    out[p] = ev;
}

extern "C" void kernel_launch(void* const* d_in, const int* in_sizes, int n_in,
                              void* d_out, int out_size, void* d_ws, size_t ws_size,
                              hipStream_t stream) {
    const float* x      = (const float*)d_in[0];
    const float* thetas = (const float*)d_in[1];
    const float* phis   = (const float*)d_in[2];
    float* out = (float*)d_out;
    const int P = out_size;               // 16 * 128 * 128 = 262144
    const int threads = 256;
    const int blocks = (P + threads - 1) / threads;
    qsim_kernel<<<blocks, threads, 0, stream>>>(x, thetas, phis, out, P);
}